// Round 10
// baseline (274.680 us; speedup 1.0000x reference)
//
#include <hip/hip_runtime.h>
#include <hip/hip_bf16.h>
#include <math.h>

// CapsNet dynamic routing. R10: persistent producer/consumer blocks.
// - Grid 256 (1 block/CU), 512 thr, each block loops over 5 (j,batch-pair)
//   items. LDS double-buffers two bf16 uhat item-tiles (147.5 KB + ce/spart).
// - Per item: waves 0-5 route item e (trio per batch, 384 rows/wave; R9's
//   verified pass structure & swizzle) while waves 6-7 stage item e+1's
//   Phase A into the other tile, in 4 chunks between the item's 4 balanced
//   barriers. Staging VMEM runs continuously under routing VALU/LDS --
//   fixes the phase serialization R7-R9 counters showed (no pipe >50%).
// - Item stride 256 keeps x=blk&7 constant: each XCD touches <=2 W j-slices.
// - exp fused into b-update (same lane owns the row; not R8's redundant
//   16-wide fusion). cexp chunk-local: written+read by the same wave.
//
// u: [256][1152][8] f32; weight: [1152][10][8][16] f32; out: [256][10][16] f32

#define IC 1152
#define OC 10
#define NB 256
#define TILE_DW (IC * 8)   // dwords per batch tile (bf16-packed)
#define NBLK 256
#define IPB 5

__device__ __forceinline__ float bf_lo(unsigned w) { return __uint_as_float(w << 16); }
__device__ __forceinline__ float bf_hi(unsigned w) { return __uint_as_float(w & 0xFFFF0000u); }
__device__ __forceinline__ unsigned pack2(float a, float b) {
    __hip_bfloat162 h = __float22bfloat162_rn(make_float2(a, b));
    return *(unsigned*)&h;
}
__device__ __forceinline__ unsigned short pack1(float a) {
    __hip_bfloat16 h = __float2bfloat16(a);
    return *(unsigned short*)&h;
}

__device__ __forceinline__ void item_map(int it, int& j, int& bb) {
    const int x = it & 7, sg = it >> 3;
    int p;
    if (sg < 128) { j = x; p = sg; }
    else { const int s2 = sg - 128; j = 8 + (x >> 2); p = ((x & 3) << 5) + s2; }
    bb = p * 2;
}

// uhat row: logical quad mq of row i lives at dwords pb,pb+1 (pb = half-XOR
// swizzle on (i>>2)&1). Stage one row's 2 batches: 8 W-quads f32 + u rows.
__device__ __forceinline__ void stage_row(unsigned* __restrict__ uhd,
                                          const float* __restrict__ uB,
                                          const float* __restrict__ W,
                                          int j, int i, int mq, int pb) {
    const float4* wrow = (const float4*)(W + ((size_t)(i * OC + j) << 7)) + mq;
    const float* ur = uB + i * 8;
    const float4 ua0 = *(const float4*)(ur);
    const float4 ua1 = *(const float4*)(ur + 4);
    const float4 ub0 = *(const float4*)(ur + IC * 8);
    const float4 ub1 = *(const float4*)(ur + IC * 8 + 4);
    float4 s0 = {0.f,0.f,0.f,0.f}, s1 = {0.f,0.f,0.f,0.f};
    float4 w4;
#define ST(ux, uy, n)                                                     \
    w4 = wrow[(n) * 4];                                                   \
    s0.x += (ux)*w4.x; s0.y += (ux)*w4.y; s0.z += (ux)*w4.z; s0.w += (ux)*w4.w; \
    s1.x += (uy)*w4.x; s1.y += (uy)*w4.y; s1.z += (uy)*w4.z; s1.w += (uy)*w4.w;
    ST(ua0.x, ub0.x, 0) ST(ua0.y, ub0.y, 1) ST(ua0.z, ub0.z, 2) ST(ua0.w, ub0.w, 3)
    ST(ua1.x, ub1.x, 4) ST(ua1.y, ub1.y, 5) ST(ua1.z, ub1.z, 6) ST(ua1.w, ub1.w, 7)
#undef ST
    const int dst = (i << 3) + pb;
    *(uint2*)&uhd[dst]           = make_uint2(pack2(s0.x, s0.y), pack2(s0.z, s0.w));
    *(uint2*)&uhd[TILE_DW + dst] = make_uint2(pack2(s1.x, s1.y), pack2(s1.z, s1.w));
}

__global__ __launch_bounds__(512, 2)
void caps_route_kernel(const float* __restrict__ u,
                       const float* __restrict__ W,
                       float* __restrict__ out) {
    extern __shared__ unsigned smem_u[];
    unsigned* uh0 = smem_u;                   // item tile A (2 batches)
    unsigned* uh1 = smem_u + 2 * TILE_DW;     // item tile B
    unsigned short* ce = (unsigned short*)(smem_u + 4 * TILE_DW);  // [2 bt][IC]
    float* spart = (float*)(ce + 2 * IC);     // [2 parity][2 bt][3 trio][20]

    const int t    = threadIdx.x;
    const int lane = t & 63;
    const int wid  = t >> 6;
    const int blk  = blockIdx.x;

    int j_cur, bb_cur;
    item_map(blk, j_cur, bb_cur);

    // ---- prologue: all 8 waves stage item 0 into uh0 (R9 Phase-A shape) ----
    {
        const int mq = t & 3, i0 = t >> 2;
        const int pb = (((mq >> 1) ^ ((i0 >> 2) & 1)) << 2) + ((mq & 1) << 1);
        const float* uB = u + (size_t)bb_cur * (IC * 8);
#pragma unroll 3
        for (int k = 0; k < 9; ++k)
            stage_row(uh0, uB, W, j_cur, i0 + 128 * k, mq, pb);
    }
    __syncthreads();

    // consumer ids (wid 0..5): trio w3 of batch bt, rows [w3*384, +384)
    const int bt = (wid >= 3) ? 1 : 0;
    const int w3 = wid - bt * 3;
    const int rowbase = w3 * 384;
    const int mqc = lane & 3;
    const int h   = lane >> 2;
    const int pbS = (((mqc >> 1) ^ ((h >> 2) & 1)) << 2) + ((mqc & 1) << 1);
    const bool eB = ((lane >> 2) & 1) != 0;
    // producer ids (wid 6..7): rows pw*576 + (lane>>2) + 16k, k = 0..35
    const int pw  = wid - 6;
    const int ibp = pw * 576 + (lane >> 2);
    const int pbP = (((mqc >> 1) ^ ((lane >> 4) & 1)) << 2) + ((mqc & 1) << 1);

    for (int e = 0; e < IPB; ++e) {
        unsigned* uh_cur = (e & 1) ? uh1 : uh0;
        unsigned* uh_nxt = (e & 1) ? uh0 : uh1;
        const bool hasNext = (e + 1 < IPB);
        int j_nxt = j_cur, bb_nxt = bb_cur;
        if (hasNext) item_map(blk + NBLK * (e + 1), j_nxt, bb_nxt);
        const float* uBn = u + (size_t)bb_nxt * (IC * 8);

        const unsigned* uhT = uh_cur + bt * TILE_DW;
        unsigned short* ceT = ce + bt * IC;
        float* spB0 = spart + bt * 60;         // parity 0 (r0, r2)
        float* spB1 = spart + 120 + bt * 60;   // parity 1 (r1)

        float4 acc = {0.f,0.f,0.f,0.f};
        float  se  = 0.f;
        float  L[6];
        float4 vq  = {0.f,0.f,0.f,0.f};

        // s-pass with coefficients from ce (rounds 1,2)
        auto spass_c = [&]() {
            acc = make_float4(0.f, 0.f, 0.f, 0.f);
#pragma unroll 6
            for (int k = 0; k < 24; ++k) {
                const int i = rowbase + 16 * k + h;
                const uint2 d = *(const uint2*)&uhT[(i << 3) + pbS];
                const float c = __uint_as_float(((unsigned)ceT[i]) << 16);
                acc.x += c * bf_lo(d.x); acc.y += c * bf_hi(d.x);
                acc.z += c * bf_lo(d.y); acc.w += c * bf_hi(d.y);
            }
#pragma unroll
            for (int o = 4; o <= 32; o <<= 1) {
                acc.x += __shfl_xor(acc.x, o, 64); acc.y += __shfl_xor(acc.y, o, 64);
                acc.z += __shfl_xor(acc.z, o, 64); acc.w += __shfl_xor(acc.w, o, 64);
            }
        };
        // combine trio partials + squash -> vq (this lane's m-quad)
        auto combine = [&](const float* spB, int r) {
            const int o1 = ((w3 + 1) % 3) * 20, o2 = ((w3 + 2) % 3) * 20;
            const float4 q1 = *(const float4*)&spB[o1 + (mqc << 2)];
            const float4 q2 = *(const float4*)&spB[o2 + (mqc << 2)];
            const float inv = (r == 0) ? (1.0f / (float)IC)
                                       : 1.0f / (se + spB[o1 + 16] + spB[o2 + 16]);
            const float4 s4 = make_float4((acc.x + q1.x + q2.x) * inv,
                                          (acc.y + q1.y + q2.y) * inv,
                                          (acc.z + q1.z + q2.z) * inv,
                                          (acc.w + q1.w + q2.w) * inv);
            float p2 = s4.x*s4.x + s4.y*s4.y + s4.z*s4.z + s4.w*s4.w;
            p2 += __shfl_xor(p2, 1, 64);
            p2 += __shfl_xor(p2, 2, 64);
            const float sc = p2 / ((1.0f + p2) * sqrtf(p2 + 1e-8f));
            vq = make_float4(s4.x * sc, s4.y * sc, s4.z * sc, s4.w * sc);
        };
        // b-update fused with next round's exp: same lane owns the row
        auto bupd_exp = [&]() {
            const float4 q0 = make_float4(__shfl(vq.x,0,4), __shfl(vq.y,0,4),
                                          __shfl(vq.z,0,4), __shfl(vq.w,0,4));
            const float4 q1 = make_float4(__shfl(vq.x,1,4), __shfl(vq.y,1,4),
                                          __shfl(vq.z,1,4), __shfl(vq.w,1,4));
            const float4 q2 = make_float4(__shfl(vq.x,2,4), __shfl(vq.y,2,4),
                                          __shfl(vq.z,2,4), __shfl(vq.w,2,4));
            const float4 q3 = make_float4(__shfl(vq.x,3,4), __shfl(vq.y,3,4),
                                          __shfl(vq.z,3,4), __shfl(vq.w,3,4));
            const float4 Qa0 = eB ? q2 : q0, Qa1 = eB ? q3 : q1;
            const float4 Qb0 = eB ? q0 : q2, Qb1 = eB ? q1 : q3;
            se = 0.f;
#pragma unroll 3
            for (int k = 0; k < 6; ++k) {
                const int i = rowbase + lane + 64 * k;
                const uint4 da = *(const uint4*)&uhT[i << 3];
                const uint4 db = *(const uint4*)&uhT[(i << 3) + 4];
                const float dot = bf_lo(da.x)*Qa0.x + bf_hi(da.x)*Qa0.y
                                + bf_lo(da.y)*Qa0.z + bf_hi(da.y)*Qa0.w
                                + bf_lo(da.z)*Qa1.x + bf_hi(da.z)*Qa1.y
                                + bf_lo(da.w)*Qa1.z + bf_hi(da.w)*Qa1.w
                                + bf_lo(db.x)*Qb0.x + bf_hi(db.x)*Qb0.y
                                + bf_lo(db.y)*Qb0.z + bf_hi(db.y)*Qb0.w
                                + bf_lo(db.z)*Qb1.x + bf_hi(db.z)*Qb1.y
                                + bf_lo(db.w)*Qb1.z + bf_hi(db.w)*Qb1.w;
                L[k] += dot;
                const float ev = __expf(L[k]);  // max-free: verified R6-R9
                ceT[i] = pack1(ev);
                se += ev;
            }
#pragma unroll
            for (int o = 32; o >= 1; o >>= 1) se += __shfl_xor(se, o, 64);
        };

        // ====== P1: r0 s-pass | producer chunk 0 ======
        if (wid < 6) {
#pragma unroll
            for (int k = 0; k < 6; ++k) L[k] = 0.f;
            acc = make_float4(0.f, 0.f, 0.f, 0.f);
#pragma unroll 6
            for (int k = 0; k < 24; ++k) {
                const int i = rowbase + 16 * k + h;
                const uint2 d = *(const uint2*)&uhT[(i << 3) + pbS];
                acc.x += bf_lo(d.x); acc.y += bf_hi(d.x);
                acc.z += bf_lo(d.y); acc.w += bf_hi(d.y);
            }
#pragma unroll
            for (int o = 4; o <= 32; o <<= 1) {
                acc.x += __shfl_xor(acc.x, o, 64); acc.y += __shfl_xor(acc.y, o, 64);
                acc.z += __shfl_xor(acc.z, o, 64); acc.w += __shfl_xor(acc.w, o, 64);
            }
            if (lane < 4) *(float4*)&spB0[w3 * 20 + (lane << 2)] = acc;
        } else if (hasNext) {
#pragma unroll 3
            for (int kk = 0; kk < 9; ++kk)
                stage_row(uh_nxt, uBn, W, j_nxt, ibp + 16 * kk, mqc, pbP);
        }
        __syncthreads();

        // ====== P2: combine r0 -> v0; bupd+exp; r1 s-pass | chunk 1 ======
        if (wid < 6) {
            combine(spB0, 0);
            bupd_exp();
            spass_c();
            if (lane < 4) *(float4*)&spB1[w3 * 20 + (lane << 2)] = acc;
            else if (lane == 4) spB1[w3 * 20 + 16] = se;
        } else if (hasNext) {
#pragma unroll 3
            for (int kk = 9; kk < 18; ++kk)
                stage_row(uh_nxt, uBn, W, j_nxt, ibp + 16 * kk, mqc, pbP);
        }
        __syncthreads();

        // ====== P3: combine r1 -> v1; bupd+exp; r2 s-pass | chunk 2 ======
        if (wid < 6) {
            combine(spB1, 1);
            bupd_exp();
            spass_c();
            if (lane < 4) *(float4*)&spB0[w3 * 20 + (lane << 2)] = acc;
            else if (lane == 4) spB0[w3 * 20 + 16] = se;
        } else if (hasNext) {
#pragma unroll 3
            for (int kk = 18; kk < 27; ++kk)
                stage_row(uh_nxt, uBn, W, j_nxt, ibp + 16 * kk, mqc, pbP);
        }
        __syncthreads();

        // ====== P4: combine r2 -> v2; output | chunk 3 ======
        if (wid < 6) {
            combine(spB0, 2);
            if (w3 == 0 && lane < 4)
                *(float4*)&out[((size_t)(bb_cur + bt) * OC + j_cur) * 16 + (lane << 2)] = vq;
        } else if (hasNext) {
#pragma unroll 3
            for (int kk = 27; kk < 36; ++kk)
                stage_row(uh_nxt, uBn, W, j_nxt, ibp + 16 * kk, mqc, pbP);
        }
        __syncthreads();  // item boundary: tile swap safe

        j_cur = j_nxt; bb_cur = bb_nxt;
    }
}

extern "C" void kernel_launch(void* const* d_in, const int* in_sizes, int n_in,
                              void* d_out, int out_size, void* d_ws, size_t ws_size,
                              hipStream_t stream) {
    const float* u = (const float*)d_in[0];
    const float* W = (const float*)d_in[1];
    float* out = (float*)d_out;

    const size_t shmem = (size_t)4 * TILE_DW * 4   // two item tiles, bf16 x 2 batches
                       + (size_t)2 * IC * 2        // ce
                       + 240 * 4;                  // spart  => 153024 B
    hipFuncSetAttribute((const void*)caps_route_kernel,
                        hipFuncAttributeMaxDynamicSharedMemorySize, (int)shmem);

    caps_route_kernel<<<NBLK, 512, shmem, stream>>>(u, W, out);
}

// Round 11
// 134.356 us; speedup vs baseline: 2.0444x; 2.0444x over previous
//
#include <hip/hip_runtime.h>
#include <hip/hip_bf16.h>
#include <math.h>

// CapsNet dynamic routing. R11: R10 pipeline, rebalanced 10P/6C in one
// 1024-thread persistent block per CU.
// - R10's 2 producer waves starved everything (VALUBusy 14%, HBM 208 GB/s):
//   staging is the LARGER work half (~10.5K cyc L2 stream + ~8K cyc VALU
//   per item vs ~6K routing). R11: waves 0-5 route item e (R10's verified
//   trio structure), waves 6-15 stage item e+1 (5x lanes + MLP).
// - Grid 256 (1 block/CU), 16 waves = 4/SIMD, (1024,4) -> VGPR cap 128
//   (pool 512/SIMD per m69; body needs ~60). LDS 153 KB double-buffered.
// - Producer work task-indexed (tau = row-quad, 4608/item) in 4 chunks
//   between the 4 balanced per-item barriers.
// - Item stride 256 keeps x=blk&7 constant: each XCD touches <=2 W j-slices.
//
// u: [256][1152][8] f32; weight: [1152][10][8][16] f32; out: [256][10][16] f32

#define IC 1152
#define OC 10
#define TILE_DW (IC * 8)   // dwords per batch tile (bf16-packed)
#define NBLK 256
#define IPB 5              // 1280 items total (10 j x 128 batch-pairs)

__device__ __forceinline__ float bf_lo(unsigned w) { return __uint_as_float(w << 16); }
__device__ __forceinline__ float bf_hi(unsigned w) { return __uint_as_float(w & 0xFFFF0000u); }
__device__ __forceinline__ unsigned pack2(float a, float b) {
    __hip_bfloat162 h = __float22bfloat162_rn(make_float2(a, b));
    return *(unsigned*)&h;
}
__device__ __forceinline__ unsigned short pack1(float a) {
    __hip_bfloat16 h = __float2bfloat16(a);
    return *(unsigned short*)&h;
}

__device__ __forceinline__ void item_map(int it, int& j, int& bb) {
    const int x = it & 7, sg = it >> 3;
    int p;
    if (sg < 128) { j = x; p = sg; }
    else { const int s2 = sg - 128; j = 8 + (x >> 2); p = ((x & 3) << 5) + s2; }
    bb = p * 2;
}

// Stage one m-quad of one row (both batches). pb = half-XOR swizzle.
__device__ __forceinline__ void stage_task(unsigned* __restrict__ uhd,
                                           const float* __restrict__ uB,
                                           const float* __restrict__ W,
                                           int j, int tau) {
    const int mq = tau & 3;
    const int i  = tau >> 2;
    const int pb = (((mq >> 1) ^ ((i >> 2) & 1)) << 2) + ((mq & 1) << 1);
    const float4* wrow = (const float4*)(W + ((size_t)(i * OC + j) << 7)) + mq;
    const float* ur = uB + i * 8;
    const float4 ua0 = *(const float4*)(ur);
    const float4 ua1 = *(const float4*)(ur + 4);
    const float4 ub0 = *(const float4*)(ur + IC * 8);
    const float4 ub1 = *(const float4*)(ur + IC * 8 + 4);
    float4 s0 = {0.f,0.f,0.f,0.f}, s1 = {0.f,0.f,0.f,0.f};
    float4 w4;
#define ST(ux, uy, n)                                                     \
    w4 = wrow[(n) * 4];                                                   \
    s0.x += (ux)*w4.x; s0.y += (ux)*w4.y; s0.z += (ux)*w4.z; s0.w += (ux)*w4.w; \
    s1.x += (uy)*w4.x; s1.y += (uy)*w4.y; s1.z += (uy)*w4.z; s1.w += (uy)*w4.w;
    ST(ua0.x, ub0.x, 0) ST(ua0.y, ub0.y, 1) ST(ua0.z, ub0.z, 2) ST(ua0.w, ub0.w, 3)
    ST(ua1.x, ub1.x, 4) ST(ua1.y, ub1.y, 5) ST(ua1.z, ub1.z, 6) ST(ua1.w, ub1.w, 7)
#undef ST
    const int dst = (i << 3) + pb;
    *(uint2*)&uhd[dst]           = make_uint2(pack2(s0.x, s0.y), pack2(s0.z, s0.w));
    *(uint2*)&uhd[TILE_DW + dst] = make_uint2(pack2(s1.x, s1.y), pack2(s1.z, s1.w));
}

__global__ __launch_bounds__(1024, 4)
void caps_route_kernel(const float* __restrict__ u,
                       const float* __restrict__ W,
                       float* __restrict__ out) {
    extern __shared__ unsigned smem_u[];
    unsigned* uh0 = smem_u;                   // item tile A (2 batches, bf16)
    unsigned* uh1 = smem_u + 2 * TILE_DW;     // item tile B
    unsigned short* ce = (unsigned short*)(smem_u + 4 * TILE_DW);  // [2 bt][IC]
    float* spart = (float*)(ce + 2 * IC);     // [2 parity][2 bt][3 trio][20]

    const int t    = threadIdx.x;
    const int lane = t & 63;
    const int wid  = t >> 6;
    const int blk  = blockIdx.x;

    int j_cur, bb_cur;
    item_map(blk, j_cur, bb_cur);

    // ---- prologue: ALL 16 waves stage item 0 into uh0 ----
    {
        const float* uB = u + (size_t)bb_cur * (IC * 8);
#pragma unroll
        for (int k = 0; k < 5; ++k) {
            const int tau = t + 1024 * k;
            if (tau < 4608) stage_task(uh0, uB, W, j_cur, tau);
        }
    }
    __syncthreads();

    // consumer ids (wid 0..5): trio w3 of batch bt, rows [w3*384, +384)
    const int bt = (wid >= 3) ? 1 : 0;        // valid for wid<6
    const int w3 = wid - bt * 3;
    const int rowbase = w3 * 384;
    const int mqc = lane & 3;
    const int h   = lane >> 2;
    const int pbS = (((mqc >> 1) ^ ((h >> 2) & 1)) << 2) + ((mqc & 1) << 1);
    const bool eB = ((lane >> 2) & 1) != 0;
    // producer ids (wid 6..15): pid in [0, 640)
    const int pid = (wid - 6) * 64 + lane;

    for (int e = 0; e < IPB; ++e) {
        unsigned* uh_cur = (e & 1) ? uh1 : uh0;
        unsigned* uh_nxt = (e & 1) ? uh0 : uh1;
        const bool hasNext = (e + 1 < IPB);
        int j_nxt = j_cur, bb_nxt = bb_cur;
        if (hasNext) item_map(blk + NBLK * (e + 1), j_nxt, bb_nxt);
        const float* uBn = u + (size_t)bb_nxt * (IC * 8);

        const unsigned* uhT = uh_cur + bt * TILE_DW;
        unsigned short* ceT = ce + bt * IC;
        float* spB0 = spart + bt * 60;         // parity 0 (r0, r2)
        float* spB1 = spart + 120 + bt * 60;   // parity 1 (r1)

        float4 acc = {0.f,0.f,0.f,0.f};
        float  se  = 0.f;
        float  L[6];
        float4 vq  = {0.f,0.f,0.f,0.f};

        // s-pass with coefficients from ce (rounds 1,2)
        auto spass_c = [&]() {
            acc = make_float4(0.f, 0.f, 0.f, 0.f);
#pragma unroll 6
            for (int k = 0; k < 24; ++k) {
                const int i = rowbase + 16 * k + h;
                const uint2 d = *(const uint2*)&uhT[(i << 3) + pbS];
                const float c = __uint_as_float(((unsigned)ceT[i]) << 16);
                acc.x += c * bf_lo(d.x); acc.y += c * bf_hi(d.x);
                acc.z += c * bf_lo(d.y); acc.w += c * bf_hi(d.y);
            }
#pragma unroll
            for (int o = 4; o <= 32; o <<= 1) {
                acc.x += __shfl_xor(acc.x, o, 64); acc.y += __shfl_xor(acc.y, o, 64);
                acc.z += __shfl_xor(acc.z, o, 64); acc.w += __shfl_xor(acc.w, o, 64);
            }
        };
        // combine trio partials + squash -> vq (this lane's m-quad)
        auto combine = [&](const float* spB, int r) {
            const int o1 = ((w3 + 1) % 3) * 20, o2 = ((w3 + 2) % 3) * 20;
            const float4 q1 = *(const float4*)&spB[o1 + (mqc << 2)];
            const float4 q2 = *(const float4*)&spB[o2 + (mqc << 2)];
            const float inv = (r == 0) ? (1.0f / (float)IC)
                                       : 1.0f / (se + spB[o1 + 16] + spB[o2 + 16]);
            const float4 s4 = make_float4((acc.x + q1.x + q2.x) * inv,
                                          (acc.y + q1.y + q2.y) * inv,
                                          (acc.z + q1.z + q2.z) * inv,
                                          (acc.w + q1.w + q2.w) * inv);
            float p2 = s4.x*s4.x + s4.y*s4.y + s4.z*s4.z + s4.w*s4.w;
            p2 += __shfl_xor(p2, 1, 64);
            p2 += __shfl_xor(p2, 2, 64);
            const float sc = p2 / ((1.0f + p2) * sqrtf(p2 + 1e-8f));
            vq = make_float4(s4.x * sc, s4.y * sc, s4.z * sc, s4.w * sc);
        };
        // b-update fused with next round's exp (same lane owns the row)
        auto bupd_exp = [&]() {
            const float4 q0 = make_float4(__shfl(vq.x,0,4), __shfl(vq.y,0,4),
                                          __shfl(vq.z,0,4), __shfl(vq.w,0,4));
            const float4 q1 = make_float4(__shfl(vq.x,1,4), __shfl(vq.y,1,4),
                                          __shfl(vq.z,1,4), __shfl(vq.w,1,4));
            const float4 q2 = make_float4(__shfl(vq.x,2,4), __shfl(vq.y,2,4),
                                          __shfl(vq.z,2,4), __shfl(vq.w,2,4));
            const float4 q3 = make_float4(__shfl(vq.x,3,4), __shfl(vq.y,3,4),
                                          __shfl(vq.z,3,4), __shfl(vq.w,3,4));
            const float4 Qa0 = eB ? q2 : q0, Qa1 = eB ? q3 : q1;
            const float4 Qb0 = eB ? q0 : q2, Qb1 = eB ? q1 : q3;
            se = 0.f;
#pragma unroll 3
            for (int k = 0; k < 6; ++k) {
                const int i = rowbase + lane + 64 * k;
                const uint4 da = *(const uint4*)&uhT[i << 3];
                const uint4 db = *(const uint4*)&uhT[(i << 3) + 4];
                const float dot = bf_lo(da.x)*Qa0.x + bf_hi(da.x)*Qa0.y
                                + bf_lo(da.y)*Qa0.z + bf_hi(da.y)*Qa0.w
                                + bf_lo(da.z)*Qa1.x + bf_hi(da.z)*Qa1.y
                                + bf_lo(da.w)*Qa1.z + bf_hi(da.w)*Qa1.w
                                + bf_lo(db.x)*Qb0.x + bf_hi(db.x)*Qb0.y
                                + bf_lo(db.y)*Qb0.z + bf_hi(db.y)*Qb0.w
                                + bf_lo(db.z)*Qb1.x + bf_hi(db.z)*Qb1.y
                                + bf_lo(db.w)*Qb1.z + bf_hi(db.w)*Qb1.w;
                L[k] += dot;
                const float ev = __expf(L[k]);  // max-free: verified R6-R10
                ceT[i] = pack1(ev);
                se += ev;
            }
#pragma unroll
            for (int o = 32; o >= 1; o >>= 1) se += __shfl_xor(se, o, 64);
        };

        // ====== P1: r0 s-pass | producer tasks k=0,1 ======
        if (wid < 6) {
#pragma unroll
            for (int k = 0; k < 6; ++k) L[k] = 0.f;
            acc = make_float4(0.f, 0.f, 0.f, 0.f);
#pragma unroll 6
            for (int k = 0; k < 24; ++k) {
                const int i = rowbase + 16 * k + h;
                const uint2 d = *(const uint2*)&uhT[(i << 3) + pbS];
                acc.x += bf_lo(d.x); acc.y += bf_hi(d.x);
                acc.z += bf_lo(d.y); acc.w += bf_hi(d.y);
            }
#pragma unroll
            for (int o = 4; o <= 32; o <<= 1) {
                acc.x += __shfl_xor(acc.x, o, 64); acc.y += __shfl_xor(acc.y, o, 64);
                acc.z += __shfl_xor(acc.z, o, 64); acc.w += __shfl_xor(acc.w, o, 64);
            }
            if (lane < 4) *(float4*)&spB0[w3 * 20 + (lane << 2)] = acc;
        } else if (hasNext) {
            stage_task(uh_nxt, uBn, W, j_nxt, pid);
            stage_task(uh_nxt, uBn, W, j_nxt, pid + 640);
        }
        __syncthreads();

        // ====== P2: combine r0 -> v0; bupd+exp; r1 s-pass | tasks k=2,3 ======
        if (wid < 6) {
            combine(spB0, 0);
            bupd_exp();
            spass_c();
            if (lane < 4) *(float4*)&spB1[w3 * 20 + (lane << 2)] = acc;
            else if (lane == 4) spB1[w3 * 20 + 16] = se;
        } else if (hasNext) {
            stage_task(uh_nxt, uBn, W, j_nxt, pid + 1280);
            stage_task(uh_nxt, uBn, W, j_nxt, pid + 1920);
        }
        __syncthreads();

        // ====== P3: combine r1 -> v1; bupd+exp; r2 s-pass | tasks k=4,5 ======
        if (wid < 6) {
            combine(spB1, 1);
            bupd_exp();
            spass_c();
            if (lane < 4) *(float4*)&spB0[w3 * 20 + (lane << 2)] = acc;
            else if (lane == 4) spB0[w3 * 20 + 16] = se;
        } else if (hasNext) {
            stage_task(uh_nxt, uBn, W, j_nxt, pid + 2560);
            stage_task(uh_nxt, uBn, W, j_nxt, pid + 3200);
        }
        __syncthreads();

        // ====== P4: combine r2 -> v2; output | tasks k=6,7(partial) ======
        if (wid < 6) {
            combine(spB0, 2);
            if (w3 == 0 && lane < 4)
                *(float4*)&out[((size_t)(bb_cur + bt) * OC + j_cur) * 16 + (lane << 2)] = vq;
        } else if (hasNext) {
            stage_task(uh_nxt, uBn, W, j_nxt, pid + 3840);
            if (pid < 128) stage_task(uh_nxt, uBn, W, j_nxt, pid + 4480);
        }
        __syncthreads();  // item boundary: tile swap safe

        j_cur = j_nxt; bb_cur = bb_nxt;
    }
}

extern "C" void kernel_launch(void* const* d_in, const int* in_sizes, int n_in,
                              void* d_out, int out_size, void* d_ws, size_t ws_size,
                              hipStream_t stream) {
    const float* u = (const float*)d_in[0];
    const float* W = (const float*)d_in[1];
    float* out = (float*)d_out;

    const size_t shmem = (size_t)4 * TILE_DW * 4   // two item tiles (2 batches, bf16)
                       + (size_t)2 * IC * 2        // ce
                       + 240 * 4;                  // spart  => 153024 B
    hipFuncSetAttribute((const void*)caps_route_kernel,
                        hipFuncAttributeMaxDynamicSharedMemorySize, (int)shmem);

    caps_route_kernel<<<NBLK, 1024, shmem, stream>>>(u, W, out);
}

// Round 12
// 124.502 us; speedup vs baseline: 2.2062x; 1.0792x over previous
//
#include <hip/hip_runtime.h>
#include <hip/hip_bf16.h>
#include <math.h>

// CapsNet dynamic routing. R12 = R9 geometry + R11's 6-wave trio routing.
// - Verdict from R10/R11: explicit producer/consumer pipelining loses to
//   plain phases (chunk barriers run at max(P,C); consumer latency floor).
//   Dropped. This round: R9's launch shape with routing parallelism x1.5.
// - Block = (j, 2 batches), grid 1280, 512 thr, LDS 77.4 KB -> 2 blocks/CU.
// - Phase A: all 8 waves (R9 verbatim). Routing: waves 0-5, trio per batch
//   (384 rows/wave: s-pass k<24, b-update k<6); exp fused into b-update
//   (same lane owns the row - R11-verified); 1 barrier per round, spart
//   parity-double-buffered; waves 6-7 mirror the 3 barriers.
// - softmax max-free (|logit| small; verified R6-R11).
//
// u: [256][1152][8] f32; weight: [1152][10][8][16] f32; out: [256][10][16] f32

#define IC 1152
#define OC 10
#define NB 256
#define TILE_DW (IC * 8)   // dwords per batch tile (bf16-packed)

__device__ __forceinline__ float bf_lo(unsigned w) { return __uint_as_float(w << 16); }
__device__ __forceinline__ float bf_hi(unsigned w) { return __uint_as_float(w & 0xFFFF0000u); }
__device__ __forceinline__ unsigned pack2(float a, float b) {
    __hip_bfloat162 h = __float22bfloat162_rn(make_float2(a, b));
    return *(unsigned*)&h;
}
__device__ __forceinline__ unsigned short pack1(float a) {
    __hip_bfloat16 h = __float2bfloat16(a);
    return *(unsigned short*)&h;
}

__global__ __launch_bounds__(512, 4)
void caps_route_kernel(const float* __restrict__ u,
                       const float* __restrict__ W,
                       float* __restrict__ out) {
    extern __shared__ unsigned smem_u[];
    unsigned* uh = smem_u;                                    // 2 tiles (73728 B)
    unsigned short* ce = (unsigned short*)(uh + 2 * TILE_DW); // [2 bt][IC] (4608 B)
    float* spart = (float*)(ce + 2 * IC);                     // [2 par][2 bt][3 trio][20]

    const int t    = threadIdx.x;
    const int bx   = blockIdx.x;
    const int lane = t & 63;
    const int wid  = t >> 6;

    // XCD-aware (j, batch-pair) mapping (xcd = bx & 7 heuristic).
    int x = bx & 7, sg = bx >> 3;
    int j, p;
    if (sg < 128) { j = x; p = sg; }
    else { int s2 = sg - 128; j = 8 + (x >> 2); p = ((x & 3) << 5) + s2; }
    const int bb = p * 2;  // batches bb, bb+1

    // ---- Phase A (R9 verbatim): uhat[B][i][m] -> LDS bf16, half-XOR swizzle ----
    {
        const int q  = t & 3;
        const int i0 = t >> 2;           // 0..127; (i>>2)&1 k-independent
        const int pb = (((q >> 1) ^ ((i0 >> 2) & 1)) << 2) + ((q & 1) << 1);
        const float* u0p = u + (size_t)bb * (IC * 8);
#pragma unroll 3
        for (int k = 0; k < 9; ++k) {
            const int i = i0 + 128 * k;
            const float4* wrow = (const float4*)(W + ((size_t)(i * OC + j) << 7)) + q;
            const float4 ua0 = *(const float4*)(u0p + i * 8);
            const float4 ua1 = *(const float4*)(u0p + i * 8 + 4);
            const float4 ub0 = *(const float4*)(u0p + IC * 8 + i * 8);
            const float4 ub1 = *(const float4*)(u0p + IC * 8 + i * 8 + 4);
            float4 s0 = {0.f,0.f,0.f,0.f}, s1 = {0.f,0.f,0.f,0.f};
            float4 w4;
#define ST(ux, uy, n)                                                     \
            w4 = wrow[(n) * 4];                                           \
            s0.x += (ux)*w4.x; s0.y += (ux)*w4.y;                         \
            s0.z += (ux)*w4.z; s0.w += (ux)*w4.w;                         \
            s1.x += (uy)*w4.x; s1.y += (uy)*w4.y;                         \
            s1.z += (uy)*w4.z; s1.w += (uy)*w4.w;
            ST(ua0.x, ub0.x, 0) ST(ua0.y, ub0.y, 1) ST(ua0.z, ub0.z, 2) ST(ua0.w, ub0.w, 3)
            ST(ua1.x, ub1.x, 4) ST(ua1.y, ub1.y, 5) ST(ua1.z, ub1.z, 6) ST(ua1.w, ub1.w, 7)
#undef ST
            const int dst = (i << 3) + pb;
            *(uint2*)&uh[dst]           = make_uint2(pack2(s0.x, s0.y), pack2(s0.z, s0.w));
            *(uint2*)&uh[TILE_DW + dst] = make_uint2(pack2(s1.x, s1.y), pack2(s1.z, s1.w));
        }
    }

    __syncthreads();  // B0: uhat ready

    if (wid >= 6) {   // barrier mirrors for the 3 per-round barriers
        __syncthreads();
        __syncthreads();
        __syncthreads();
        return;
    }

    // ---- Routing: trio w3 of batch bt owns rows [w3*384, +384) ----
    const int bt = (wid >= 3) ? 1 : 0;
    const int w3 = wid - bt * 3;
    const int rowbase = w3 * 384;
    const unsigned* uhT = uh + bt * TILE_DW;
    unsigned short* ceT = ce + bt * IC;
    float* spB[2] = { spart + bt * 60, spart + 120 + bt * 60 };

    const int mqc = lane & 3;
    const int h   = lane >> 2;
    const int pbS = (((mqc >> 1) ^ ((h >> 2) & 1)) << 2) + ((mqc & 1) << 1);
    const bool eB = ((lane >> 2) & 1) != 0;

    float L[6];
#pragma unroll
    for (int k = 0; k < 6; ++k) L[k] = 0.f;
    float se = 0.f;
    float4 acc, vq;

    for (int r = 0; r < 3; ++r) {
        // ---- s-pass over own 384 rows (c from ce for r>0; same-wave LDS) ----
        acc = make_float4(0.f, 0.f, 0.f, 0.f);
        if (r == 0) {
#pragma unroll 6
            for (int k = 0; k < 24; ++k) {
                const int i = rowbase + 16 * k + h;
                const uint2 d = *(const uint2*)&uhT[(i << 3) + pbS];
                acc.x += bf_lo(d.x); acc.y += bf_hi(d.x);
                acc.z += bf_lo(d.y); acc.w += bf_hi(d.y);
            }
        } else {
#pragma unroll 6
            for (int k = 0; k < 24; ++k) {
                const int i = rowbase + 16 * k + h;
                const uint2 d = *(const uint2*)&uhT[(i << 3) + pbS];
                const float c = __uint_as_float(((unsigned)ceT[i]) << 16);
                acc.x += c * bf_lo(d.x); acc.y += c * bf_hi(d.x);
                acc.z += c * bf_lo(d.y); acc.w += c * bf_hi(d.y);
            }
        }
#pragma unroll
        for (int o = 4; o <= 32; o <<= 1) {   // reduce over h within wave
            acc.x += __shfl_xor(acc.x, o, 64); acc.y += __shfl_xor(acc.y, o, 64);
            acc.z += __shfl_xor(acc.z, o, 64); acc.w += __shfl_xor(acc.w, o, 64);
        }
        float* sp = spB[r & 1];
        if (lane < 4) *(float4*)&sp[w3 * 20 + (lane << 2)] = acc;
        else if (r > 0 && lane == 4) sp[w3 * 20 + 16] = se;
        __syncthreads();  // B(r+1)

        // ---- combine trio partials + squash -> vq ----
        {
            const int o1 = ((w3 + 1) % 3) * 20, o2 = ((w3 + 2) % 3) * 20;
            const float4 q1 = *(const float4*)&sp[o1 + (mqc << 2)];
            const float4 q2 = *(const float4*)&sp[o2 + (mqc << 2)];
            const float inv = (r == 0) ? (1.0f / (float)IC)
                                       : 1.0f / (se + sp[o1 + 16] + sp[o2 + 16]);
            const float4 s4 = make_float4((acc.x + q1.x + q2.x) * inv,
                                          (acc.y + q1.y + q2.y) * inv,
                                          (acc.z + q1.z + q2.z) * inv,
                                          (acc.w + q1.w + q2.w) * inv);
            float p2 = s4.x*s4.x + s4.y*s4.y + s4.z*s4.z + s4.w*s4.w;
            p2 += __shfl_xor(p2, 1, 64);
            p2 += __shfl_xor(p2, 2, 64);
            const float sc = p2 / ((1.0f + p2) * sqrtf(p2 + 1e-8f));
            vq = make_float4(s4.x * sc, s4.y * sc, s4.z * sc, s4.w * sc);
        }

        if (r == 2) {
            if (w3 == 0 && lane < 4)
                *(float4*)&out[((size_t)(bb + bt) * OC + j) * 16 + (lane << 2)] = vq;
        } else {
            // ---- b-update fused with exp (same lane owns the row) ----
            const float4 q0 = make_float4(__shfl(vq.x,0,4), __shfl(vq.y,0,4),
                                          __shfl(vq.z,0,4), __shfl(vq.w,0,4));
            const float4 q1 = make_float4(__shfl(vq.x,1,4), __shfl(vq.y,1,4),
                                          __shfl(vq.z,1,4), __shfl(vq.w,1,4));
            const float4 q2 = make_float4(__shfl(vq.x,2,4), __shfl(vq.y,2,4),
                                          __shfl(vq.z,2,4), __shfl(vq.w,2,4));
            const float4 q3 = make_float4(__shfl(vq.x,3,4), __shfl(vq.y,3,4),
                                          __shfl(vq.z,3,4), __shfl(vq.w,3,4));
            const float4 Qa0 = eB ? q2 : q0, Qa1 = eB ? q3 : q1;
            const float4 Qb0 = eB ? q0 : q2, Qb1 = eB ? q1 : q3;
            se = 0.f;
#pragma unroll 3
            for (int k = 0; k < 6; ++k) {
                const int i = rowbase + lane + 64 * k;
                const uint4 da = *(const uint4*)&uhT[i << 3];
                const uint4 db = *(const uint4*)&uhT[(i << 3) + 4];
                const float dot = bf_lo(da.x)*Qa0.x + bf_hi(da.x)*Qa0.y
                                + bf_lo(da.y)*Qa0.z + bf_hi(da.y)*Qa0.w
                                + bf_lo(da.z)*Qa1.x + bf_hi(da.z)*Qa1.y
                                + bf_lo(da.w)*Qa1.z + bf_hi(da.w)*Qa1.w
                                + bf_lo(db.x)*Qb0.x + bf_hi(db.x)*Qb0.y
                                + bf_lo(db.y)*Qb0.z + bf_hi(db.y)*Qb0.w
                                + bf_lo(db.z)*Qb1.x + bf_hi(db.z)*Qb1.y
                                + bf_lo(db.w)*Qb1.z + bf_hi(db.w)*Qb1.w;
                L[k] += dot;
                const float ev = __expf(L[k]);  // max-free: verified R6-R11
                ceT[i] = pack1(ev);
                se += ev;
            }
#pragma unroll
            for (int o = 32; o >= 1; o >>= 1) se += __shfl_xor(se, o, 64);
        }
    }
}

extern "C" void kernel_launch(void* const* d_in, const int* in_sizes, int n_in,
                              void* d_out, int out_size, void* d_ws, size_t ws_size,
                              hipStream_t stream) {
    const float* u = (const float*)d_in[0];
    const float* W = (const float*)d_in[1];
    float* out = (float*)d_out;

    const size_t shmem = (size_t)2 * TILE_DW * 4   // two batch tiles (bf16)
                       + (size_t)2 * IC * 2        // ce
                       + 240 * 4;                  // spart => 79296 B
    hipFuncSetAttribute((const void*)caps_route_kernel,
                        hipFuncAttributeMaxDynamicSharedMemorySize, (int)shmem);

    caps_route_kernel<<<(NB / 2) * OC, 512, shmem, stream>>>(u, W, out);
}